// Round 12
// baseline (208.459 us; speedup 1.0000x reference)
//
#include <hip/hip_runtime.h>

#define NI 2048
#define NB 64
#define NC 32
#define DC 16
#define DI 8

static constexpr float SQ_EPS = 1e-7f;

// SSA vector type: first-class LLVM vector -> never an alloca, never scratch.
typedef float f8 __attribute__((ext_vector_type(8)));

// Routing pass v13 — small blocks, BIG GRID: the untested occupancy channel.
// Ledger: every attempt to raise waves/CU from 512 workgroups failed
// (hints v2/v3/v7/v8; small-LDS v4/v5 was grid-limited; reg pipelines
// spill v9; per-lane W streams uncoalesced v11). v12's DMA dbuf works
// (45.4 us, 0 bank conflicts, no spill) but is still 2 waves/EU latency-
// bound (both pipes <45% busy). v13: 1024 workgroups of 36 KB so the
// dispatcher packs 4 blocks/CU = 16 waves/CU = 4 waves/EU from RESOURCES
// (no hints): split the i-range, not b -> per-wave W amortization over
// 4 b is preserved -> per-CU LDS/VALU work is IDENTICAL to v12; worst
// case (packing still pinned) is neutral, best case ~1.5x.
// Block = 16 b x NIB i (NIB=8 main, 16 fallback), 4 waves, wave owns the
// b-quad by*16 + w*4 + {0..3}. NIB rounds of 1 i, double-buffered 16 KB
// W tiles staged by global_load_lds (no VGPR round-trip -> spill-proof),
// rotation layout slot(q,cc) = q*32 + ((cc+q)&31) (linear 64-lane chunks
// for the DMA, 0 conflicts measured in v12). x staged once (32*NIB f4).
// LDS = 2*16 KB + 128*NIB B. Attrs (2,8): min=2 -> 128-reg budget (law:
// 256/min; v12 live set 124 fits), max=8 -> no runtime wave clamp (v7
// lesson; v8 proved (2,8) codegen is clean).
// Lane = (c = lane&31, dg = lane>>5).
// MODE 0: uniform coupling 1/32. MODE 1: logits = dot(u, veff),
// veff transposed [b][dg][c][8].
template <int MODE, int NIB>
__global__
__attribute__((amdgpu_flat_work_group_size(256, 256), amdgpu_waves_per_eu(2, 8)))
void route_pass(
    const float* __restrict__ x, const float* __restrict__ W,
    const float* __restrict__ veff, float* __restrict__ partial)
{
    __shared__ float4 wbuf[2][1024];      // rotation layout, 2 x 16 KB
    __shared__ float4 xbuf[32 * NIB];     // [brel 16][iloc NIB][2], once

    const int tid   = threadIdx.x;
    const int wave  = tid >> 6;
    const int lane  = tid & 63;
    const int c     = lane & 31;
    const int dg    = lane >> 5;
    const int brel0 = wave * 4;
    const int b0    = blockIdx.y * 16 + brel0;    // wave's b-quad base
    const int i0    = blockIdx.x * NIB;

    const float4* Wf4 = reinterpret_cast<const float4*>(W);

    f8 s0 = {}, s1 = {}, s2 = {}, s3 = {};

    // veff fragments for the 4 b's (MODE 1), transposed [b][dg][c][8]
    f8 va = {}, vb = {}, vc = {}, vd = {};
    if (MODE == 1) {
        va = *reinterpret_cast<const f8*>(veff + (((size_t)(b0+0)*2 + dg)*32 + c)*8);
        vb = *reinterpret_cast<const f8*>(veff + (((size_t)(b0+1)*2 + dg)*32 + c)*8);
        vc = *reinterpret_cast<const f8*>(veff + (((size_t)(b0+2)*2 + dg)*32 + c)*8);
        vd = *reinterpret_cast<const f8*>(veff + (((size_t)(b0+3)*2 + dg)*32 + c)*8);
    }

    // ---- async stage of one 1-i W tile (1024 f4) into wbuf[buf].
    // slot s: q = s>>5 (f4-in-row 0..31), cc = ((s&31) - q)&31;
    // global f4 = (cc*NI + it)*32 + q.  4 wave-ops x 1 KB linear dest.
#define STAGE_ASYNC(buf, it)                                                 \
    {                                                                        \
        _Pragma("unroll")                                                    \
        for (int o = 0; o < 4; ++o) {                                        \
            const int s  = o * 256 + wave * 64 + lane;                       \
            const int q  = s >> 5;                                           \
            const int cc = ((s & 31) - q) & 31;                              \
            const float4* srcp = Wf4 + ((size_t)cc * NI + (it)) * 32 + q;    \
            __builtin_amdgcn_global_load_lds(                                \
                (const __attribute__((address_space(1))) void*)srcp,         \
                (__attribute__((address_space(3))) void*)&wbuf[buf][o * 256 + wave * 64], \
                16, 0, 0);                                                   \
        }                                                                    \
    }

    // ---- prologue: issue tile 0; stage x once (coalesced within b-rows)
    STAGE_ASYNC(0, i0);
    {
        const float4* xg = reinterpret_cast<const float4*>(x);
#pragma unroll
        for (int t = tid; t < 32 * NIB; t += 256) {
            const int brel = t / (NIB * 2);
            const int rem  = t % (NIB * 2);
            xbuf[t] = xg[((size_t)(blockIdx.y * 16 + brel) * NI + i0 + (rem >> 1)) * 2 + (rem & 1)];
        }
    }
    __syncthreads();      // drains DMA (tile 0 ready) + xbuf visible

    int cur = 0;
    for (int rnd = 0; rnd < NIB; ++rnd) {
        // issue next tile first: latency hides under this round's compute
        if (rnd < NIB - 1) STAGE_ASYNC(cur ^ 1, i0 + rnd + 1);

        const float4* wb = wbuf[cur];

        // x broadcast reads (wave-uniform LDS addresses)
        const float4 xa0 = xbuf[(brel0+0)*(NIB*2) + rnd*2], xa1 = xbuf[(brel0+0)*(NIB*2) + rnd*2+1];
        const float4 xb0 = xbuf[(brel0+1)*(NIB*2) + rnd*2], xb1 = xbuf[(brel0+1)*(NIB*2) + rnd*2+1];
        const float4 xc0 = xbuf[(brel0+2)*(NIB*2) + rnd*2], xc1 = xbuf[(brel0+2)*(NIB*2) + rnd*2+1];
        const float4 xd0 = xbuf[(brel0+3)*(NIB*2) + rnd*2], xd1 = xbuf[(brel0+3)*(NIB*2) + rnd*2+1];

        f8 u0 = {}, u1 = {}, u2 = {}, u3 = {};
#pragma unroll
        for (int dd = 0; dd < 8; ++dd) {
            const int q0 = (dg * 8 + dd) * 2;        // f4-in-row of d's low half
            const float4 wl = wb[ q0      * 32 + ((c + q0    ) & 31)];
            const float4 wh = wb[(q0 + 1) * 32 + ((c + q0 + 1) & 31)];
            u0[dd] = wl.x*xa0.x + wl.y*xa0.y + wl.z*xa0.z + wl.w*xa0.w
                   + wh.x*xa1.x + wh.y*xa1.y + wh.z*xa1.z + wh.w*xa1.w;
            u1[dd] = wl.x*xb0.x + wl.y*xb0.y + wl.z*xb0.z + wl.w*xb0.w
                   + wh.x*xb1.x + wh.y*xb1.y + wh.z*xb1.z + wh.w*xb1.w;
            u2[dd] = wl.x*xc0.x + wl.y*xc0.y + wl.z*xc0.z + wl.w*xc0.w
                   + wh.x*xc1.x + wh.y*xc1.y + wh.z*xc1.z + wh.w*xc1.w;
            u3[dd] = wl.x*xd0.x + wl.y*xd0.y + wl.z*xd0.z + wl.w*xd0.w
                   + wh.x*xd1.x + wh.y*xd1.y + wh.z*xd1.z + wh.w*xd1.w;
        }

        if (MODE == 0) {
            const float cu = 1.0f / 32.0f;
            s0 += u0 * cu; s1 += u1 * cu; s2 += u2 * cu; s3 += u3 * cu;
        } else {
            // Pair-softmax: lower 32-half reduces the even b, upper the
            // odd b, concurrently; one xor-32 merge in, one xor-32
            // coef-swap out. 12 shuffles + 1 exp per pair.
#pragma unroll
            for (int pr = 0; pr < 2; ++pr) {
                const f8& ue = pr ? u2 : u0;
                const f8& uo = pr ? u3 : u1;
                const f8& ve = pr ? vc : va;
                const f8& vo = pr ? vd : vb;
                float pe = 0.0f, po = 0.0f;
#pragma unroll
                for (int kk = 0; kk < 8; ++kk) {
                    pe += ue[kk] * ve[kk];
                    po += uo[kk] * vo[kk];
                }
                // route partial of the OTHER half's b across, keep mine
                const float send = (dg == 0) ? po : pe;
                const float recv = __shfl_xor(send, 32);
                float a = ((dg == 0) ? pe : po) + recv;  // full logit
                float m = a;
#pragma unroll
                for (int off = 16; off >= 1; off >>= 1)
                    m = fmaxf(m, __shfl_xor(m, off));
                const float e = __expf(a - m);
                float t = e;
#pragma unroll
                for (int off = 16; off >= 1; off >>= 1)
                    t += __shfl_xor(t, off);
                const float mine  = e / t;
                const float other = __shfl_xor(mine, 32);
                const float ce = (dg == 0) ? mine : other;
                const float co = (dg == 0) ? other : mine;
                if (pr == 0) { s0 += u0 * ce; s1 += u1 * co; }
                else         { s2 += u2 * ce; s3 += u3 * co; }
            }
        }

        __syncthreads();   // drains vmcnt (next tile landed under compute)
        cur ^= 1;          // + all readers of wbuf[cur] done
    }
#undef STAGE_ASYNC

    // ---- flush the wave's four s-partials (plain coalesced 32 B stores)
    // partial floats: [pblk][brel 16][dg 2][c 32][8]
    {
        const int pblk = blockIdx.y * gridDim.x + blockIdx.x;
        float* gp = partial +
            (((size_t)pblk * 16 + brel0) * 128 + dg * 64 + c * 2) * 4;
        *reinterpret_cast<f8*>(gp)        = s0;
        *reinterpret_cast<f8*>(gp +  512) = s1;
        *reinterpret_cast<f8*>(gp + 1024) = s2;
        *reinterpret_cast<f8*>(gp + 1536) = s3;
    }
}

// Fused SLABS-way partial reduction + squash, float4-vectorized.
// 64 blocks x 512 threads: ibq = tid>>7 sums SLABS/4 slabs; sub = tid&127
// -> (c, dq). 4-way LDS tree then squash on tid<128.
// phase 1: veff  = NI * squash(s)   (transposed layout [b][dg][c][8])
// phase 2: veff += NI * squash(s)
// phase 3: out   = squash(s)        (canonical [b][c][d])
template <int SLABS>
__global__ __launch_bounds__(512) void reduce_squash(
    const float* __restrict__ partial, float* __restrict__ veff,
    float* __restrict__ out, int phase)
{
    __shared__ float4 red[512];
    const int b   = blockIdx.x;
    const int sub = threadIdx.x & 127;
    const int ibq = threadIdx.x >> 7;        // slab quarter
    const int c   = (sub >> 2) & 31;
    const int dq  = sub & 3;                 // d-quad: d = dq*4 + j

    // slab layout: [by*SLABS + ib][brel 16][dg 2][c 32][8]
    const float* base = partial
        + ((size_t)(b >> 4) * SLABS * 16 + (b & 15)) * 512
        + (dq >> 1) * 256 + c * 8 + (dq & 1) * 4
        + (size_t)ibq * (SLABS / 4) * 8192;
    float4 acc = make_float4(0.f, 0.f, 0.f, 0.f);
#pragma unroll 8
    for (int ib = 0; ib < SLABS / 4; ++ib) {
        const float4 p = *reinterpret_cast<const float4*>(base + (size_t)ib * 8192);
        acc.x += p.x; acc.y += p.y; acc.z += p.z; acc.w += p.w;
    }
    red[threadIdx.x] = acc;
    __syncthreads();
    if (threadIdx.x < 128) {
        const float4 a1 = red[sub + 128];
        const float4 a2 = red[sub + 256];
        const float4 a3 = red[sub + 384];
        acc.x += a1.x + a2.x + a3.x;
        acc.y += a1.y + a2.y + a3.y;
        acc.z += a1.z + a2.z + a3.z;
        acc.w += a1.w + a2.w + a3.w;

        // |s|^2 across the 4 d-quads (dq = low 2 bits of lane id)
        float sq = acc.x*acc.x + acc.y*acc.y + acc.z*acc.z + acc.w*acc.w;
        sq += __shfl_xor(sq, 1);
        sq += __shfl_xor(sq, 2);
        const float scale = sq / ((1.0f + sq) * sqrtf(sq + SQ_EPS));

        if (phase == 3) {
            float4* op = reinterpret_cast<float4*>(out + ((size_t)b * NC + c) * DC + dq * 4);
            *op = make_float4(scale*acc.x, scale*acc.y, scale*acc.z, scale*acc.w);
        } else {
            const float ns = scale * (float)NI;
            float4* vp = reinterpret_cast<float4*>(
                veff + (((size_t)b * 2 + (dq >> 1)) * 32 + c) * 8 + (dq & 1) * 4);
            if (phase == 1) {
                *vp = make_float4(ns*acc.x, ns*acc.y, ns*acc.z, ns*acc.w);
            } else {
                float4 old = *vp;
                *vp = make_float4(old.x + ns*acc.x, old.y + ns*acc.y,
                                  old.z + ns*acc.z, old.w + ns*acc.w);
            }
        }
    }
}

extern "C" void kernel_launch(void* const* d_in, const int* in_sizes, int n_in,
                              void* d_out, int out_size, void* d_ws, size_t ws_size,
                              hipStream_t stream) {
    (void)in_sizes; (void)n_in; (void)out_size;
    const float* x = (const float*)d_in[0];
    const float* W = (const float*)d_in[1];

    float* partial = (float*)d_ws;
    float* veff    = (float*)d_out;     // scratch; phase-3 squash overwrites

    // Main path: 1024 blocks of 8 i -> needs 1024*16*512*4 = 33.6 MB ws.
    if (ws_size >= (size_t)1024 * 16 * 512 * 4) {
        const dim3 grid(256, 4);
        route_pass<0, 8><<<grid, 256, 0, stream>>>(x, W, nullptr, partial);
        reduce_squash<256><<<64, 512, 0, stream>>>(partial, veff, nullptr, 1);
        route_pass<1, 8><<<grid, 256, 0, stream>>>(x, W, veff, partial);
        reduce_squash<256><<<64, 512, 0, stream>>>(partial, veff, nullptr, 2);
        route_pass<1, 8><<<grid, 256, 0, stream>>>(x, W, veff, partial);
        reduce_squash<256><<<64, 512, 0, stream>>>(partial, nullptr, (float*)d_out, 3);
    } else {
        // Fallback (16 MiB ws): v12-equivalent geometry, 1-i rounds.
        const dim3 grid(128, 4);
        route_pass<0, 16><<<grid, 256, 0, stream>>>(x, W, nullptr, partial);
        reduce_squash<128><<<64, 512, 0, stream>>>(partial, veff, nullptr, 1);
        route_pass<1, 16><<<grid, 256, 0, stream>>>(x, W, veff, partial);
        reduce_squash<128><<<64, 512, 0, stream>>>(partial, veff, nullptr, 2);
        route_pass<1, 16><<<grid, 256, 0, stream>>>(x, W, veff, partial);
        reduce_squash<128><<<64, 512, 0, stream>>>(partial, nullptr, (float*)d_out, 3);
    }
}